// Round 1
// baseline (914.417 us; speedup 1.0000x reference)
//
#include <hip/hip_runtime.h>
#include <stdint.h>

typedef __attribute__((ext_vector_type(8))) short short8;
typedef __attribute__((ext_vector_type(4))) float f32x4;
typedef __attribute__((ext_vector_type(4))) unsigned short us4;

#define MFMA16(a,b,c) __builtin_amdgcn_mfma_f32_16x16x32_bf16((a),(b),(c),0,0,0)

static __device__ __forceinline__ float bf2f(unsigned short u){
  union { float f; unsigned int i; } c; c.i = ((unsigned int)u) << 16; return c.f;
}
static __device__ __forceinline__ unsigned short f2bf(float f){
  union { float f; unsigned int i; } c; c.f = f;
  unsigned int x = c.i;
  unsigned int r = x + 0x7fffu + ((x >> 16) & 1u);
  return (unsigned short)(r >> 16);
}

typedef const __attribute__((address_space(1))) void cg_void;
typedef __attribute__((address_space(3))) void lds_void;
static __device__ __forceinline__ void gl_lds16(const void* g, void* l){
  __builtin_amdgcn_global_load_lds((cg_void*)g, (lds_void*)l, 16, 0, 0);
}

// ---------------- convert g: f32 [10000][10000] -> bf16 [10000][10048], pad cols zero ----------------
__global__ void k_conv_g(const float* __restrict__ g, unsigned short* __restrict__ o){
  const int CH = 2512; // 10048/4 chunks per row
  const long long total = 10000LL * CH;
  for (long long i = (long long)blockIdx.x*blockDim.x + threadIdx.x; i < total;
       i += (long long)gridDim.x*blockDim.x){
    int r = (int)(i / CH);
    int c4 = (int)(i % CH) * 4;
    us4 v = {0,0,0,0};
    if (c4 < 10000){
      float4 f = *(const float4*)(g + (long long)r*10000 + c4);
      v.x = f2bf(f.x); v.y = f2bf(f.y); v.z = f2bf(f.z); v.w = f2bf(f.w);
    }
    *(us4*)(o + (long long)r*10048 + c4) = v;
  }
}

// ---------------- generic f32 -> bf16 (weights) ----------------
__global__ void k_conv(const float* __restrict__ in, unsigned short* __restrict__ o, int n4){
  for (int i = blockIdx.x*blockDim.x + threadIdx.x; i < n4; i += gridDim.x*blockDim.x){
    float4 f = *(const float4*)(in + (long long)i*4);
    us4 v; v.x=f2bf(f.x); v.y=f2bf(f.y); v.z=f2bf(f.z); v.w=f2bf(f.w);
    *(us4*)(o + (long long)i*4) = v;
  }
}

// ---------------- transpose-convert z: f32 [10000][128] -> bf16 [128][10048] ----------------
// grid (157, 2), block 256
__global__ void k_tconv_z(const float* __restrict__ z, unsigned short* __restrict__ o){
  __shared__ unsigned short t[64][65];
  const int rb = blockIdx.x*64, cb = blockIdx.y*64;
  #pragma unroll
  for (int it = 0; it < 4; ++it){
    int idx = it*256 + threadIdx.x;
    int r = idx >> 4, c4 = (idx & 15) * 4;
    float4 f = {0.f,0.f,0.f,0.f};
    if (rb + r < 10000) f = *(const float4*)(z + (long long)(rb+r)*128 + cb + c4);
    t[c4+0][r] = f2bf(f.x); t[c4+1][r] = f2bf(f.y);
    t[c4+2][r] = f2bf(f.z); t[c4+3][r] = f2bf(f.w);
  }
  __syncthreads();
  #pragma unroll
  for (int it = 0; it < 4; ++it){
    int idx = it*256 + threadIdx.x;
    int ro = idx >> 4, co4 = (idx & 15) * 4;
    us4 v; v.x=t[ro][co4]; v.y=t[ro][co4+1]; v.z=t[ro][co4+2]; v.w=t[ro][co4+3];
    *(us4*)(o + (long long)(cb+ro)*10048 + rb + co4) = v;
  }
}

// ---------------- transpose bf16: [10000][256] -> [256][10048] ----------------
// grid (157, 4), block 256
__global__ void k_t_bf16(const unsigned short* __restrict__ in, unsigned short* __restrict__ o){
  __shared__ unsigned short t[64][65];
  const int rb = blockIdx.x*64, cb = blockIdx.y*64;
  #pragma unroll
  for (int it = 0; it < 4; ++it){
    int idx = it*256 + threadIdx.x;
    int r = idx >> 4, c4 = (idx & 15) * 4;
    us4 v = {0,0,0,0};
    if (rb + r < 10000) v = *(const us4*)(in + (long long)(rb+r)*256 + cb + c4);
    t[c4+0][r]=v.x; t[c4+1][r]=v.y; t[c4+2][r]=v.z; t[c4+3][r]=v.w;
  }
  __syncthreads();
  #pragma unroll
  for (int it = 0; it < 4; ++it){
    int idx = it*256 + threadIdx.x;
    int ro = idx >> 4, co4 = (idx & 15)*4;
    us4 v; v.x=t[ro][co4]; v.y=t[ro][co4+1]; v.z=t[ro][co4+2]; v.w=t[ro][co4+3];
    *(us4*)(o + (long long)(cb+ro)*10048 + rb + co4) = v;
  }
}

// ---------------- row L2-normalize bf16 [10000][256] ----------------
// grid 2500, block 256 (4 waves, one row per wave)
__global__ void k_rownorm(const unsigned short* __restrict__ in, unsigned short* __restrict__ o){
  const int w = threadIdx.x >> 6, l = threadIdx.x & 63;
  const int row = blockIdx.x*4 + w;
  us4 v = *(const us4*)(in + (long long)row*256 + l*4);
  float a = bf2f(v.x), b = bf2f(v.y), c = bf2f(v.z), d = bf2f(v.w);
  float ss = a*a + b*b + c*c + d*d;
  #pragma unroll
  for (int off = 32; off; off >>= 1) ss += __shfl_xor(ss, off, 64);
  float s = 1.0f / fmaxf(sqrtf(ss), 1e-12f);
  us4 r; r.x=f2bf(a*s); r.y=f2bf(b*s); r.z=f2bf(c*s); r.w=f2bf(d*s);
  *(us4*)(o + (long long)row*256 + l*4) = r;
}

// ---------------- big GEMM: C = epi(A @ B^T) ----------------
// A: g16 bf16 [10000][10048]; B: bf16 [N][10048]; tile BM=80 x BN=64, BK=64, 5 waves.
// EPI: 0 = store bf16; 1 = appnp bf16 (0.5*acc + 0.5*H); 2 = appnp f32
template<int EPI>
__global__ __launch_bounds__(320)
void k_gemm_big(const unsigned short* __restrict__ A,
                const unsigned short* __restrict__ B,
                void* __restrict__ Cout,
                const unsigned short* __restrict__ H,
                int ldc)
{
  constexpr int LDA = 10048;
  constexpr int KT  = 157;       // 10048/64
  __shared__ unsigned short sm[2][(80+64)*64]; // A tile then B tile, 16B chunks xor-swizzled

  const int tid = threadIdx.x, w = tid >> 6, l = tid & 63;
  const int mBase = blockIdx.x * 80, nBase = blockIdx.y * 64;

  // staging: chunk = (slot*64 + lane); slot layout: A slots w, w+5 ; B slots w, (w+5 if w<3)
  const int chunk = w*64 + l;
  const int rA = chunk >> 3, cA = chunk & 7;
  const long long offA = (long long)(mBase + rA)*LDA + ((cA ^ (rA & 7)) * 8);
  const long long offB = (long long)(nBase + rA)*LDA + ((cA ^ (rA & 7)) * 8);
  const bool doB1 = (w < 3);

  auto stage = [&](int buf, int kt){
    const unsigned short* Ak = A + (long long)kt*64;
    const unsigned short* Bk = B + (long long)kt*64;
    unsigned short* dst = &sm[buf][0];
    gl_lds16(Ak + offA,                 dst + w*512);
    gl_lds16(Ak + offA + 40LL*LDA,      dst + (w+5)*512);
    gl_lds16(Bk + offB,                 dst + 80*64 + w*512);
    if (doB1) gl_lds16(Bk + offB + 40LL*LDA, dst + 80*64 + (w+5)*512);
  };

  f32x4 acc[4];
  #pragma unroll
  for (int f = 0; f < 4; ++f){ f32x4 zz = {0.f,0.f,0.f,0.f}; acc[f] = zz; }

  const int lr = l & 15, lk = l >> 4, swz = l & 7;
  const int aRow = (16*w + lr)*64;

  stage(0, 0);
  for (int kt = 0; kt < KT; ++kt){
    __syncthreads();
    if (kt + 1 < KT) stage((kt+1)&1, kt+1);
    const unsigned short* s = &sm[kt&1][0];
    #pragma unroll
    for (int ks = 0; ks < 2; ++ks){
      short8 a = *(const short8*)(s + aRow + (((4*ks + lk) ^ swz) * 8));
      #pragma unroll
      for (int f = 0; f < 4; ++f){
        short8 b = *(const short8*)(s + 80*64 + (16*f + lr)*64 + (((4*ks + lk) ^ swz) * 8));
        acc[f] = MFMA16(a, b, acc[f]);
      }
    }
  }

  const int row0 = mBase + 16*w + lk*4;
  #pragma unroll
  for (int f = 0; f < 4; ++f){
    const int col = nBase + 16*f + lr;
    #pragma unroll
    for (int r = 0; r < 4; ++r){
      const long long idx = (long long)(row0 + r)*ldc + col;
      float v = acc[f][r];
      if constexpr (EPI == 0){
        ((unsigned short*)Cout)[idx] = f2bf(v);
      } else {
        float h = bf2f(H[idx]);
        float zv = 0.5f*v + 0.5f*h;
        if constexpr (EPI == 1) ((unsigned short*)Cout)[idx] = f2bf(zv);
        else                    ((float*)Cout)[idx] = zv;
      }
    }
  }
}

// ---------------- small GEMM: out = act(A @ W^T) ----------------
// A bf16 [10000][KW]; W bf16 [NW][KW]; ACT 0: relu->bf16, 1: sigmoid->f32
template<int NW, int KW, int ACT>
__global__ __launch_bounds__(320)
void k_gemm_small(const unsigned short* __restrict__ A,
                  const unsigned short* __restrict__ W,
                  void* __restrict__ out)
{
  const int tid = threadIdx.x, w = tid >> 6, l = tid & 63;
  const int lr = l & 15, lk = l >> 4;
  const int mBase = blockIdx.x * 80;
  constexpr int NF = NW/16;

  f32x4 acc[NF];
  #pragma unroll
  for (int f = 0; f < NF; ++f){ f32x4 zz = {0.f,0.f,0.f,0.f}; acc[f] = zz; }

  const unsigned short* ap = A + (long long)(mBase + 16*w + lr)*KW + lk*8;
  #pragma unroll
  for (int kc = 0; kc < KW/32; ++kc){
    short8 a = *(const short8*)(ap + kc*32);
    #pragma unroll
    for (int f = 0; f < NF; ++f){
      short8 b = *(const short8*)(W + (long long)(16*f + lr)*KW + kc*32 + lk*8);
      acc[f] = MFMA16(a, b, acc[f]);
    }
  }

  const int row0 = mBase + 16*w + lk*4;
  #pragma unroll
  for (int f = 0; f < NF; ++f){
    const int col = 16*f + lr;
    #pragma unroll
    for (int r = 0; r < 4; ++r){
      const long long idx = (long long)(row0 + r)*NW + col;
      float v = acc[f][r];
      if constexpr (ACT == 0) ((unsigned short*)out)[idx] = f2bf(fmaxf(v, 0.0f));
      else                    ((float*)out)[idx] = 1.0f / (1.0f + expf(-v));
    }
  }
}

extern "C" void kernel_launch(void* const* d_in, const int* in_sizes, int n_in,
                              void* d_out, int out_size, void* d_ws, size_t ws_size,
                              hipStream_t stream)
{
  const float* g   = (const float*)d_in[0];
  const float* z   = (const float*)d_in[1];
  const float* W1  = (const float*)d_in[2];
  const float* W1_ = (const float*)d_in[3];
  const float* W2  = (const float*)d_in[4];

  char* ws = (char*)d_ws;
  size_t off = 0;
  auto alloc = [&](size_t bytes)->void*{
    void* p = ws + off; off += (bytes + 255) & ~(size_t)255; return p;
  };
  unsigned short* g16  = (unsigned short*)alloc(10000ULL*10048*2); // 201 MB
  unsigned short* zT   = (unsigned short*)alloc(128ULL*10048*2);
  unsigned short* W1c  = (unsigned short*)alloc(256ULL*128*2);
  unsigned short* W1_c = (unsigned short*)alloc(256ULL*256*2);
  unsigned short* W2c  = (unsigned short*)alloc(128ULL*256*2);
  unsigned short* tbuf = (unsigned short*)alloc(10000ULL*256*2);   // t0/t1/t2
  unsigned short* Xbuf = (unsigned short*)alloc(10000ULL*256*2);   // z1/z_/Z1/Z2
  unsigned short* Tbuf = (unsigned short*)alloc(256ULL*10048*2);   // transposed operand
  unsigned short* zn   = (unsigned short*)alloc(10000ULL*256*2);
  unsigned short* znT  = (unsigned short*)alloc(256ULL*10048*2);
  (void)ws_size; (void)in_sizes; (void)n_in; (void)out_size;

  float* res  = (float*)d_out;                    // [10000][128]
  float* Zout = (float*)d_out + 10000LL*128;      // [10000][256]

  // conversions
  k_conv_g<<<dim3(2048), dim3(256), 0, stream>>>(g, g16);
  k_tconv_z<<<dim3(157,2), dim3(256), 0, stream>>>(z, zT);
  k_conv<<<dim3(32), dim3(256), 0, stream>>>(W1,  W1c,  256*128/4);
  k_conv<<<dim3(64), dim3(256), 0, stream>>>(W1_, W1_c, 256*256/4);
  k_conv<<<dim3(32), dim3(256), 0, stream>>>(W2,  W2c,  128*256/4);

  // t0 = g @ z  -> [10000][128] bf16
  k_gemm_big<0><<<dim3(125,2), dim3(320), 0, stream>>>(g16, zT, tbuf, nullptr, 128);
  // z1 = relu(t0 @ W1^T) -> [10000][256] bf16
  k_gemm_small<256,128,0><<<dim3(125), dim3(320), 0, stream>>>(tbuf, W1c, Xbuf);
  k_t_bf16<<<dim3(157,4), dim3(256), 0, stream>>>(Xbuf, Tbuf);           // z1^T
  // t1 = g @ z1 -> [10000][256]
  k_gemm_big<0><<<dim3(125,4), dim3(320), 0, stream>>>(g16, Tbuf, tbuf, nullptr, 256);
  // z_ = relu(t1 @ W1_^T)
  k_gemm_small<256,256,0><<<dim3(125), dim3(320), 0, stream>>>(tbuf, W1_c, Xbuf);
  // zn = rownorm(z_)
  k_rownorm<<<dim3(2500), dim3(256), 0, stream>>>(Xbuf, zn);
  k_t_bf16<<<dim3(157,4), dim3(256), 0, stream>>>(zn, znT);              // zn^T
  k_t_bf16<<<dim3(157,4), dim3(256), 0, stream>>>(Xbuf, Tbuf);           // z_^T
  // t2 = g @ z_
  k_gemm_big<0><<<dim3(125,4), dim3(320), 0, stream>>>(g16, Tbuf, tbuf, nullptr, 256);
  // res = sigmoid(t2 @ W2^T) -> f32 d_out
  k_gemm_small<128,256,1><<<dim3(125), dim3(320), 0, stream>>>(tbuf, W2c, res);
  // Z1 = 0.5*(g@zn) + 0.5*zn
  k_gemm_big<1><<<dim3(125,4), dim3(320), 0, stream>>>(g16, znT, Xbuf, zn, 256);
  k_t_bf16<<<dim3(157,4), dim3(256), 0, stream>>>(Xbuf, Tbuf);           // Z1^T
  // Z2 = 0.5*(g@Z1) + 0.5*zn
  k_gemm_big<1><<<dim3(125,4), dim3(320), 0, stream>>>(g16, Tbuf, Xbuf, zn, 256);
  k_t_bf16<<<dim3(157,4), dim3(256), 0, stream>>>(Xbuf, Tbuf);           // Z2^T
  // Z3 = 0.5*(g@Z2) + 0.5*zn -> f32 d_out
  k_gemm_big<2><<<dim3(125,4), dim3(320), 0, stream>>>(g16, Tbuf, Zout, zn, 256);
}

// Round 2
// 632.372 us; speedup vs baseline: 1.4460x; 1.4460x over previous
//
#include <hip/hip_runtime.h>
#include <stdint.h>

typedef __attribute__((ext_vector_type(8))) short short8;
typedef __attribute__((ext_vector_type(4))) float f32x4;
typedef __attribute__((ext_vector_type(4))) unsigned short us4;

#define MFMA16(a,b,c) __builtin_amdgcn_mfma_f32_16x16x32_bf16((a),(b),(c),0,0,0)

static __device__ __forceinline__ float bf2f(unsigned short u){
  union { float f; unsigned int i; } c; c.i = ((unsigned int)u) << 16; return c.f;
}
static __device__ __forceinline__ unsigned short f2bf(float f){
  union { float f; unsigned int i; } c; c.f = f;
  unsigned int x = c.i;
  unsigned int r = x + 0x7fffu + ((x >> 16) & 1u);
  return (unsigned short)(r >> 16);
}

typedef const __attribute__((address_space(1))) void cg_void;
typedef __attribute__((address_space(3))) void lds_void;
static __device__ __forceinline__ void gl_lds16(const void* g, void* l){
  __builtin_amdgcn_global_load_lds((cg_void*)g, (lds_void*)l, 16, 0, 0);
}

// ---- convert g: f32 [10000][10000] -> bf16 [10048][10048], pad rows+cols zero ----
__global__ void k_conv_g(const float* __restrict__ g, unsigned short* __restrict__ o){
  const int CH = 2512; // 10048/4 chunks per row
  const long long total = 10048LL * CH;
  for (long long i = (long long)blockIdx.x*blockDim.x + threadIdx.x; i < total;
       i += (long long)gridDim.x*blockDim.x){
    int r = (int)(i / CH);
    int c4 = (int)(i % CH) * 4;
    us4 v = {0,0,0,0};
    if (r < 10000 && c4 < 10000){
      float4 f = *(const float4*)(g + (long long)r*10000 + c4);
      v.x = f2bf(f.x); v.y = f2bf(f.y); v.z = f2bf(f.z); v.w = f2bf(f.w);
    }
    *(us4*)(o + (long long)r*10048 + c4) = v;
  }
}

// ---- generic f32 -> bf16 (weights) ----
__global__ void k_conv(const float* __restrict__ in, unsigned short* __restrict__ o, int n4){
  for (int i = blockIdx.x*blockDim.x + threadIdx.x; i < n4; i += gridDim.x*blockDim.x){
    float4 f = *(const float4*)(in + (long long)i*4);
    us4 v; v.x=f2bf(f.x); v.y=f2bf(f.y); v.z=f2bf(f.z); v.w=f2bf(f.w);
    *(us4*)(o + (long long)i*4) = v;
  }
}

// ---- transpose-convert z: f32 [10000][128] -> bf16 [128][10048] ----
__global__ void k_tconv_z(const float* __restrict__ z, unsigned short* __restrict__ o){
  __shared__ unsigned short t[64][65];
  const int rb = blockIdx.x*64, cb = blockIdx.y*64;
  #pragma unroll
  for (int it = 0; it < 4; ++it){
    int idx = it*256 + threadIdx.x;
    int r = idx >> 4, c4 = (idx & 15) * 4;
    float4 f = {0.f,0.f,0.f,0.f};
    if (rb + r < 10000) f = *(const float4*)(z + (long long)(rb+r)*128 + cb + c4);
    t[c4+0][r] = f2bf(f.x); t[c4+1][r] = f2bf(f.y);
    t[c4+2][r] = f2bf(f.z); t[c4+3][r] = f2bf(f.w);
  }
  __syncthreads();
  #pragma unroll
  for (int it = 0; it < 4; ++it){
    int idx = it*256 + threadIdx.x;
    int ro = idx >> 4, co4 = (idx & 15) * 4;
    us4 v; v.x=t[ro][co4]; v.y=t[ro][co4+1]; v.z=t[ro][co4+2]; v.w=t[ro][co4+3];
    *(us4*)(o + (long long)(cb+ro)*10048 + rb + co4) = v;
  }
}

// ---- transpose bf16: [10000][256] -> [256][10048] ----
__global__ void k_t_bf16(const unsigned short* __restrict__ in, unsigned short* __restrict__ o){
  __shared__ unsigned short t[64][65];
  const int rb = blockIdx.x*64, cb = blockIdx.y*64;
  #pragma unroll
  for (int it = 0; it < 4; ++it){
    int idx = it*256 + threadIdx.x;
    int r = idx >> 4, c4 = (idx & 15) * 4;
    us4 v = {0,0,0,0};
    if (rb + r < 10000) v = *(const us4*)(in + (long long)(rb+r)*256 + cb + c4);
    t[c4+0][r]=v.x; t[c4+1][r]=v.y; t[c4+2][r]=v.z; t[c4+3][r]=v.w;
  }
  __syncthreads();
  #pragma unroll
  for (int it = 0; it < 4; ++it){
    int idx = it*256 + threadIdx.x;
    int ro = idx >> 4, co4 = (idx & 15)*4;
    us4 v; v.x=t[ro][co4]; v.y=t[ro][co4+1]; v.z=t[ro][co4+2]; v.w=t[ro][co4+3];
    *(us4*)(o + (long long)(cb+ro)*10048 + rb + co4) = v;
  }
}

// ---- row L2-normalize bf16 [10000][256] ----
__global__ void k_rownorm(const unsigned short* __restrict__ in, unsigned short* __restrict__ o){
  const int w = threadIdx.x >> 6, l = threadIdx.x & 63;
  const int row = blockIdx.x*4 + w;
  us4 v = *(const us4*)(in + (long long)row*256 + l*4);
  float a = bf2f(v.x), b = bf2f(v.y), c = bf2f(v.z), d = bf2f(v.w);
  float ss = a*a + b*b + c*c + d*d;
  #pragma unroll
  for (int off = 32; off; off >>= 1) ss += __shfl_xor(ss, off, 64);
  float s = 1.0f / fmaxf(sqrtf(ss), 1e-12f);
  us4 r; r.x=f2bf(a*s); r.y=f2bf(b*s); r.z=f2bf(c*s); r.w=f2bf(d*s);
  *(us4*)(o + (long long)row*256 + l*4) = r;
}

// ---- big GEMM, split-K: P[s] = A[mTile, kRange(s)] @ B^T ----
// A bf16 [10048][10048]; B bf16 [>=nBase+BN][10048]; P f32 [S][10048][ldp]
// BM=64, 4 waves as NWM x NWN, wave tile (64/NWM) x (BN/NWN)
template<int BN, int NWM, int NWN>
__global__ __launch_bounds__(256)
void k_gemm(const unsigned short* __restrict__ A,
            const unsigned short* __restrict__ B,
            float* __restrict__ P, int S, int ldp)
{
  constexpr int LDA = 10048;
  constexpr int BM  = 64;
  constexpr int WM = BM / NWM, WN = BN / NWN;
  constexpr int MF = WM / 16, NF = WN / 16;
  constexpr int AE = BM * 64;          // A tile elems
  constexpr int BE = BN * 64;
  constexpr int ACH = BM * 8 / 256;    // gl_lds16 issues per thread (A)
  constexpr int BCH = BN * 8 / 256;

  __shared__ unsigned short sm[2][AE + BE];

  const int tid = threadIdx.x, w = tid >> 6, l = tid & 63;
  const int lr = l & 15, lk = l >> 4, swz = l & 7;
  const int wm = w / NWN, wn = w % NWN;
  const int mBase = blockIdx.x * BM;
  const int nBase = blockIdx.y * BN;
  const int s = blockIdx.z;
  const int kt0 = (157 * s) / S, kt1 = (157 * (s + 1)) / S;

  auto stage = [&](int buf, int kt){
    unsigned short* dst = &sm[buf][0];
    const unsigned short* Ak = A + (long long)kt * 64;
    const unsigned short* Bk = B + (long long)kt * 64;
    #pragma unroll
    for (int i = 0; i < ACH; ++i){
      int c = i * 256 + tid;
      int row = c >> 3, gr = c & 7;
      gl_lds16(Ak + (long long)(mBase + row) * LDA + ((gr ^ (row & 7)) * 8),
               dst + c * 8);
    }
    #pragma unroll
    for (int i = 0; i < BCH; ++i){
      int c = i * 256 + tid;
      int row = c >> 3, gr = c & 7;
      gl_lds16(Bk + (long long)(nBase + row) * LDA + ((gr ^ (row & 7)) * 8),
               dst + AE + c * 8);
    }
  };

  f32x4 acc[MF][NF];
  #pragma unroll
  for (int i = 0; i < MF; ++i)
    #pragma unroll
    for (int j = 0; j < NF; ++j){ f32x4 zz = {0.f,0.f,0.f,0.f}; acc[i][j] = zz; }

  stage(0, kt0);
  int cur = 0;
  for (int kt = kt0; kt < kt1; ++kt){
    __syncthreads();
    if (kt + 1 < kt1) stage(cur ^ 1, kt + 1);
    const unsigned short* sp = &sm[cur][0];
    #pragma unroll
    for (int ks = 0; ks < 2; ++ks){
      short8 a[MF], b[NF];
      #pragma unroll
      for (int i = 0; i < MF; ++i){
        int row = wm * WM + i * 16 + lr;
        a[i] = *(const short8*)(sp + row * 64 + (((4*ks + lk) ^ swz) * 8));
      }
      #pragma unroll
      for (int j = 0; j < NF; ++j){
        int row = wn * WN + j * 16 + lr;
        b[j] = *(const short8*)(sp + AE + row * 64 + (((4*ks + lk) ^ swz) * 8));
      }
      #pragma unroll
      for (int i = 0; i < MF; ++i)
        #pragma unroll
        for (int j = 0; j < NF; ++j)
          acc[i][j] = MFMA16(a[i], b[j], acc[i][j]);
    }
    cur ^= 1;
  }

  float* Pp = P + (long long)s * 10048 * ldp;
  #pragma unroll
  for (int i = 0; i < MF; ++i){
    const int row0 = mBase + wm * WM + i * 16 + lk * 4;
    #pragma unroll
    for (int j = 0; j < NF; ++j){
      const int col = nBase + wn * WN + j * 16 + lr;
      #pragma unroll
      for (int r = 0; r < 4; ++r)
        Pp[(long long)(row0 + r) * ldp + col] = acc[i][j][r];
    }
  }
}

// ---- reduce partials + epilogue ----
// EPI 0: bf16 store; 1: 0.5*sum+0.5*H -> bf16; 2: 0.5*sum+0.5*H -> f32
template<int EPI>
__global__ void k_reduce(const float* __restrict__ P, int S, int ldp, int colOff,
                         int lg, void* __restrict__ out, int ldc,
                         const unsigned short* __restrict__ H)
{
  const long long stride = 10048LL * ldp;
  const int idx = blockIdx.x * 256 + threadIdx.x;
  const int row = idx >> lg;
  const int c4 = (idx & ((1 << lg) - 1)) * 4;
  const float* p = P + (long long)row * ldp + colOff + c4;
  float4 sv = *(const float4*)p;
  for (int s2 = 1; s2 < S; ++s2){
    float4 t = *(const float4*)(p + (long long)s2 * stride);
    sv.x += t.x; sv.y += t.y; sv.z += t.z; sv.w += t.w;
  }
  if constexpr (EPI >= 1){
    us4 h = *(const us4*)(H + (long long)row * 256 + c4);
    sv.x = 0.5f*sv.x + 0.5f*bf2f(h.x);
    sv.y = 0.5f*sv.y + 0.5f*bf2f(h.y);
    sv.z = 0.5f*sv.z + 0.5f*bf2f(h.z);
    sv.w = 0.5f*sv.w + 0.5f*bf2f(h.w);
  }
  if constexpr (EPI == 2){
    *(float4*)((float*)out + (long long)row * ldc + c4) = sv;
  } else {
    us4 o; o.x=f2bf(sv.x); o.y=f2bf(sv.y); o.z=f2bf(sv.z); o.w=f2bf(sv.w);
    *(us4*)((unsigned short*)out + (long long)row * ldc + c4) = o;
  }
}

// ---- small GEMM: out = act(A @ W^T), A bf16 [10000][KW], W bf16 [NW][KW] ----
template<int NW, int KW, int ACT>
__global__ __launch_bounds__(320)
void k_gemm_small(const unsigned short* __restrict__ A,
                  const unsigned short* __restrict__ W,
                  void* __restrict__ out)
{
  const int tid = threadIdx.x, w = tid >> 6, l = tid & 63;
  const int lr = l & 15, lk = l >> 4;
  const int mBase = blockIdx.x * 80;
  constexpr int NF = NW/16;

  f32x4 acc[NF];
  #pragma unroll
  for (int f = 0; f < NF; ++f){ f32x4 zz = {0.f,0.f,0.f,0.f}; acc[f] = zz; }

  const unsigned short* ap = A + (long long)(mBase + 16*w + lr)*KW + lk*8;
  #pragma unroll
  for (int kc = 0; kc < KW/32; ++kc){
    short8 a = *(const short8*)(ap + kc*32);
    #pragma unroll
    for (int f = 0; f < NF; ++f){
      short8 b = *(const short8*)(W + (long long)(16*f + lr)*KW + kc*32 + lk*8);
      acc[f] = MFMA16(a, b, acc[f]);
    }
  }

  const int row0 = mBase + 16*w + lk*4;
  #pragma unroll
  for (int f = 0; f < NF; ++f){
    const int col = 16*f + lr;
    #pragma unroll
    for (int r = 0; r < 4; ++r){
      const long long idx = (long long)(row0 + r)*NW + col;
      float v = acc[f][r];
      if constexpr (ACT == 0) ((unsigned short*)out)[idx] = f2bf(fmaxf(v, 0.0f));
      else                    ((float*)out)[idx] = 1.0f / (1.0f + expf(-v));
    }
  }
}

extern "C" void kernel_launch(void* const* d_in, const int* in_sizes, int n_in,
                              void* d_out, int out_size, void* d_ws, size_t ws_size,
                              hipStream_t stream)
{
  const float* g   = (const float*)d_in[0];
  const float* z   = (const float*)d_in[1];
  const float* W1  = (const float*)d_in[2];
  const float* W1_ = (const float*)d_in[3];
  const float* W2  = (const float*)d_in[4];

  char* ws = (char*)d_ws;
  size_t off = 0;
  auto alloc = [&](size_t bytes)->void*{
    void* p = ws + off; off += (bytes + 255) & ~(size_t)255; return p;
  };
  unsigned short* g16  = (unsigned short*)alloc(10048ULL*10048*2); // 202 MB
  unsigned short* zT   = (unsigned short*)alloc(128ULL*10048*2);
  unsigned short* W1c  = (unsigned short*)alloc(256ULL*128*2);
  unsigned short* W1_c = (unsigned short*)alloc(256ULL*256*2);
  unsigned short* W2c  = (unsigned short*)alloc(128ULL*256*2);
  unsigned short* tbuf = (unsigned short*)alloc(10000ULL*256*2);   // t0/t1/t2
  unsigned short* Xbuf = (unsigned short*)alloc(10000ULL*256*2);   // z1/z_/Z1/Z2
  unsigned short* Tbuf = (unsigned short*)alloc(512ULL*10048*2);   // B operand (transposed)
  unsigned short* zn   = (unsigned short*)alloc(10000ULL*256*2);
  float*          P    = (float*)alloc(10048ULL*1024*4);           // 41 MB partials
  (void)ws_size; (void)in_sizes; (void)n_in; (void)out_size;

  float* res  = (float*)d_out;                    // [10000][128]
  float* Zout = (float*)d_out + 10000LL*128;      // [10000][256]

  // conversions
  k_conv_g<<<dim3(2048), dim3(256), 0, stream>>>(g, g16);
  k_tconv_z<<<dim3(157,2), dim3(256), 0, stream>>>(z, zT);
  k_conv<<<dim3(32), dim3(256), 0, stream>>>(W1,  W1c,  256*128/4);
  k_conv<<<dim3(64), dim3(256), 0, stream>>>(W1_, W1_c, 256*256/4);
  k_conv<<<dim3(32), dim3(256), 0, stream>>>(W2,  W2c,  128*256/4);

  // t0 = g @ z  (N=128, S=3)
  k_gemm<128,2,2><<<dim3(157,1,3), dim3(256), 0, stream>>>(g16, zT, P, 3, 128);
  k_reduce<0><<<dim3(1250), dim3(256), 0, stream>>>(P, 3, 128, 0, 5, tbuf, 128, nullptr);
  // z1 = relu(t0 @ W1^T)
  k_gemm_small<256,128,0><<<dim3(125), dim3(320), 0, stream>>>(tbuf, W1c, Xbuf);
  k_t_bf16<<<dim3(157,4), dim3(256), 0, stream>>>(Xbuf, Tbuf);              // z1^T
  // t1 = g @ z1 (N=256, S=3)
  k_gemm<256,1,4><<<dim3(157,1,3), dim3(256), 0, stream>>>(g16, Tbuf, P, 3, 256);
  k_reduce<0><<<dim3(2500), dim3(256), 0, stream>>>(P, 3, 256, 0, 6, tbuf, 256, nullptr);
  // z_ = relu(t1 @ W1_^T)
  k_gemm_small<256,256,0><<<dim3(125), dim3(320), 0, stream>>>(tbuf, W1_c, Xbuf);
  // zn = rownorm(z_)
  k_rownorm<<<dim3(2500), dim3(256), 0, stream>>>(Xbuf, zn);
  k_t_bf16<<<dim3(157,4), dim3(256), 0, stream>>>(Xbuf, Tbuf);              // z_^T
  k_t_bf16<<<dim3(157,4), dim3(256), 0, stream>>>(zn, Tbuf + 256LL*10048);  // zn^T
  // [t2 | g@zn] = g @ [z_ | zn]  (N=512, S=2)
  k_gemm<256,1,4><<<dim3(157,2,2), dim3(256), 0, stream>>>(g16, Tbuf, P, 2, 512);
  k_reduce<0><<<dim3(2500), dim3(256), 0, stream>>>(P, 2, 512, 0,   6, tbuf, 256, nullptr);
  k_reduce<1><<<dim3(2500), dim3(256), 0, stream>>>(P, 2, 512, 256, 6, Xbuf, 256, zn); // Z1
  // res = sigmoid(t2 @ W2^T) -> f32 d_out
  k_gemm_small<128,256,1><<<dim3(125), dim3(320), 0, stream>>>(tbuf, W2c, res);
  // Z2 = 0.5*(g@Z1) + 0.5*zn
  k_t_bf16<<<dim3(157,4), dim3(256), 0, stream>>>(Xbuf, Tbuf);              // Z1^T
  k_gemm<256,1,4><<<dim3(157,1,3), dim3(256), 0, stream>>>(g16, Tbuf, P, 3, 256);
  k_reduce<1><<<dim3(2500), dim3(256), 0, stream>>>(P, 3, 256, 0, 6, Xbuf, 256, zn);   // Z2
  // Z3 = 0.5*(g@Z2) + 0.5*zn -> f32 d_out
  k_t_bf16<<<dim3(157,4), dim3(256), 0, stream>>>(Xbuf, Tbuf);              // Z2^T
  k_gemm<256,1,4><<<dim3(157,1,3), dim3(256), 0, stream>>>(g16, Tbuf, P, 3, 256);
  k_reduce<2><<<dim3(2500), dim3(256), 0, stream>>>(P, 3, 256, 0, 6, Zout, 256, zn);
}